// Round 1
// baseline (247.461 us; speedup 1.0000x reference)
//
#include <hip/hip_runtime.h>

#define NB 8
#define NC 2048
#define KIN 128
#define NF 64

#define MSTRIDE 2052          // mask row stride (bytes), breaks 2048 bank alias
#define HSTRIDE 132           // k1 LDS H row stride (floats)
#define WTSTRIDE 136          // k1 LDS W^T row stride (ushorts)
#define RSTRIDE 68            // k2 reduce row stride (floats)

typedef float floatx4_t __attribute__((ext_vector_type(4)));
typedef __bf16 bf16x8_t __attribute__((ext_vector_type(8)));
typedef unsigned short ushort8_t __attribute__((ext_vector_type(8)));

static __device__ __forceinline__ unsigned short f2bf(float f) {
  union { float f; unsigned int u; } v; v.f = f;
  unsigned int u = v.u;
  u += 0x7FFFu + ((u >> 16) & 1u);   // RNE; inputs never NaN
  return (unsigned short)(u >> 16);
}

static __device__ __forceinline__ float lrelu(float x) {
  return x > 0.0f ? x : 0.2f * x;
}

// ---------------------------------------------------------------------------
// Kernel 1: per block = 64 rows of one batch.
//   - w1 = W@a1, w2 = W@a2 (tiny, recomputed per block)
//   - s1[b,c] = H[b,c,:]·w1, s2 likewise (fp32 exact path for the logits)
//   - WhT[b,f,c] = bf16((H@W)^T) via MFMA: D = W^T (f x k) · H^T (k x c)
// ---------------------------------------------------------------------------
__global__ __launch_bounds__(256, 2) void k1_prep(
    const float* __restrict__ H, const float* __restrict__ W,
    const float* __restrict__ avec,
    float* __restrict__ s1g, float* __restrict__ s2g,
    unsigned short* __restrict__ WhT)
{
  __shared__ float Hsh[64 * HSTRIDE];              // 33.8 KB
  __shared__ unsigned short WTsh[NF * WTSTRIDE];   // 17.4 KB
  __shared__ float w1sh[KIN];
  __shared__ float w2sh[KIN];

  const int t = threadIdx.x;
  const int b = blockIdx.x >> 5;
  const int c0 = (blockIdx.x & 31) * 64;

  // build bf16 W^T in LDS
  for (int i = t; i < KIN * NF; i += 256) {
    int k = i >> 6, f = i & 63;
    WTsh[f * WTSTRIDE + k] = f2bf(W[i]);
  }
  // w1/w2
  if (t < KIN) {
    float acc1 = 0.f, acc2 = 0.f;
    const float* wr = W + t * NF;
#pragma unroll
    for (int f = 0; f < NF; ++f) {
      float wv = wr[f];
      acc1 += wv * avec[f];
      acc2 += wv * avec[NF + f];
    }
    w1sh[t] = acc1;
    w2sh[t] = acc2;
  }
  __syncthreads();

  const int wave = t >> 6;
  const int lane = t & 63;

  // phase 1: s1/s2 + stage H tile into LDS
  const float w1a = w1sh[2 * lane], w1b = w1sh[2 * lane + 1];
  const float w2a = w2sh[2 * lane], w2b = w2sh[2 * lane + 1];
  for (int i = 0; i < 16; ++i) {
    const int row = wave * 16 + i;
    const float* hp = H + (size_t)(b * NC + c0 + row) * KIN + 2 * lane;
    float2 hv = *(const float2*)hp;
    *(float2*)(Hsh + row * HSTRIDE + 2 * lane) = hv;
    float p1 = hv.x * w1a + hv.y * w1b;
    float p2 = hv.x * w2a + hv.y * w2b;
#pragma unroll
    for (int off = 32; off >= 1; off >>= 1) {
      p1 += __shfl_xor(p1, off);
      p2 += __shfl_xor(p2, off);
    }
    if (lane == 0) {
      s1g[b * NC + c0 + row] = p1;
      s2g[b * NC + c0 + row] = p2;
    }
  }
  __syncthreads();

  // phase 2: MFMA, D = W^T · H^T  (M = f = 64, N = c = 16 per wave, K = 128)
  const int m = lane & 15;   // A-row (f sub) and B-col (c sub)
  const int q = lane >> 4;
  floatx4_t acc[4];
#pragma unroll
  for (int mt = 0; mt < 4; ++mt) acc[mt] = (floatx4_t){0.f, 0.f, 0.f, 0.f};

#pragma unroll
  for (int kt = 0; kt < 4; ++kt) {
    const int kbase = kt * 32 + q * 8;
    const float* hb = Hsh + (wave * 16 + m) * HSTRIDE + kbase;
    float4 h0 = *(const float4*)(hb);
    float4 h1 = *(const float4*)(hb + 4);
    ushort8_t bu;
    bu[0] = f2bf(h0.x); bu[1] = f2bf(h0.y); bu[2] = f2bf(h0.z); bu[3] = f2bf(h0.w);
    bu[4] = f2bf(h1.x); bu[5] = f2bf(h1.y); bu[6] = f2bf(h1.z); bu[7] = f2bf(h1.w);
    bf16x8_t bf = __builtin_bit_cast(bf16x8_t, bu);
#pragma unroll
    for (int mt = 0; mt < 4; ++mt) {
      ushort8_t au = *(const ushort8_t*)(WTsh + (mt * 16 + m) * WTSTRIDE + kbase);
      bf16x8_t af = __builtin_bit_cast(bf16x8_t, au);
      acc[mt] = __builtin_amdgcn_mfma_f32_16x16x32_bf16(af, bf, acc[mt], 0, 0, 0);
    }
  }
  // D[row = q*4+i2 -> f][col = m -> c]
#pragma unroll
  for (int mt = 0; mt < 4; ++mt) {
#pragma unroll
    for (int i2 = 0; i2 < 4; ++i2) {
      const int f = mt * 16 + q * 4 + i2;
      WhT[(size_t)(b * NF + f) * NC + c0 + wave * 16 + m] = f2bf(acc[mt][i2]);
    }
  }
}

// ---------------------------------------------------------------------------
// Kernel 2: per block = 16 query rows of one batch. Fused mask+softmax+PV.
// ---------------------------------------------------------------------------
__global__ __launch_bounds__(256, 2) void k2_attn(
    const int* __restrict__ A, const float* __restrict__ s1g,
    const float* __restrict__ s2g, const unsigned short* __restrict__ WhT,
    float* __restrict__ out)
{
  __shared__ float s2_sh[NC];                       // 8 KB
  __shared__ unsigned char mask_sh[16 * MSTRIDE];   // 32.8 KB
  __shared__ float s1_sh[16];
  __shared__ float rmax_sh[16];
  __shared__ float rinv_sh[16];
  __shared__ float red_sh[4 * 16 * RSTRIDE];        // 17.4 KB

  const int t = threadIdx.x;
  const int b = blockIdx.x >> 7;
  const int i0 = (blockIdx.x & 127) * 16;

  // stage s2 row and s1 tile
  {
    const float* sp = s2g + b * NC;
#pragma unroll
    for (int i = 0; i < 2; ++i) {
      int j = (i * 256 + t) * 4;
      *(float4*)(s2_sh + j) = *(const float4*)(sp + j);
    }
  }
  if (t < 16) s1_sh[t] = s1g[b * NC + i0 + t];
  __syncthreads();

  const int r = t >> 4;
  const int c4 = t & 15;
  const float s1r = s1_sh[r];
  const int gi = i0 + r;
  const int* Ap = A + ((size_t)b * NC + gi) * NC;

  // ---- pass 1a: read A (the big HBM stream), store masks, row max ----
  float mmax = -3.0e38f;
#pragma unroll 4
  for (int jt = 0; jt < 32; ++jt) {
    const int j0 = jt * 64 + c4 * 4;
    int4 a4 = *(const int4*)(Ap + j0);
    float4 sv = *(const float4*)(s2_sh + j0);
    float e0 = lrelu(s1r + sv.x);
    float e1 = lrelu(s1r + sv.y);
    float e2 = lrelu(s1r + sv.z);
    float e3 = lrelu(s1r + sv.w);
    bool k0 = (a4.x > 0) || (gi == j0 + 0);
    bool k1 = (a4.y > 0) || (gi == j0 + 1);
    bool k2 = (a4.z > 0) || (gi == j0 + 2);
    bool k3 = (a4.w > 0) || (gi == j0 + 3);
    mmax = fmaxf(mmax, k0 ? e0 : -3.0e38f);
    mmax = fmaxf(mmax, k1 ? e1 : -3.0e38f);
    mmax = fmaxf(mmax, k2 ? e2 : -3.0e38f);
    mmax = fmaxf(mmax, k3 ? e3 : -3.0e38f);
    uchar4 mk;
    mk.x = (unsigned char)k0; mk.y = (unsigned char)k1;
    mk.z = (unsigned char)k2; mk.w = (unsigned char)k3;
    *(uchar4*)(mask_sh + r * MSTRIDE + j0) = mk;
  }
#pragma unroll
  for (int off = 1; off < 16; off <<= 1)
    mmax = fmaxf(mmax, __shfl_xor(mmax, off));
  if (c4 == 0) rmax_sh[r] = mmax;
  __syncthreads();

  // ---- pass 1b: denominator ----
  const float rmax = rmax_sh[r];
  float lsum = 0.f;
#pragma unroll 4
  for (int jt = 0; jt < 32; ++jt) {
    const int j0 = jt * 64 + c4 * 4;
    uchar4 mk = *(const uchar4*)(mask_sh + r * MSTRIDE + j0);
    float4 sv = *(const float4*)(s2_sh + j0);
    lsum += mk.x ? __expf(lrelu(s1r + sv.x) - rmax) : 0.f;
    lsum += mk.y ? __expf(lrelu(s1r + sv.y) - rmax) : 0.f;
    lsum += mk.z ? __expf(lrelu(s1r + sv.z) - rmax) : 0.f;
    lsum += mk.w ? __expf(lrelu(s1r + sv.w) - rmax) : 0.f;
  }
#pragma unroll
  for (int off = 1; off < 16; off <<= 1)
    lsum += __shfl_xor(lsum, off);
  if (c4 == 0) rinv_sh[r] = 1.0f / lsum;
  __syncthreads();

  // ---- pass 2: P (in MFMA A-layout) @ WhT, 4 waves split K ----
  const int wave = t >> 6;
  const int lane = t & 63;
  const int m = lane & 15;   // A-row (i sub) and B-col (f sub)
  const int q = lane >> 4;
  const float s1m = s1_sh[m];
  const float rmaxm = rmax_sh[m];
  const unsigned short* whb = WhT + (size_t)b * NF * NC;

  floatx4_t acc[4];
#pragma unroll
  for (int nt = 0; nt < 4; ++nt) acc[nt] = (floatx4_t){0.f, 0.f, 0.f, 0.f};

  for (int kt = wave * 16; kt < wave * 16 + 16; ++kt) {
    const int jq = kt * 32 + q * 8;
    const unsigned char* mp = mask_sh + m * MSTRIDE + jq;
    const unsigned int mk0 = *(const unsigned int*)(mp);
    const unsigned int mk1 = *(const unsigned int*)(mp + 4);
    const float* sp = s2_sh + jq;
    float4 sv0 = *(const float4*)(sp);
    float4 sv1 = *(const float4*)(sp + 4);
    float svv[8] = {sv0.x, sv0.y, sv0.z, sv0.w, sv1.x, sv1.y, sv1.z, sv1.w};
    ushort8_t au;
#pragma unroll
    for (int idx = 0; idx < 8; ++idx) {
      float p = __expf(lrelu(s1m + svv[idx]) - rmaxm);
      unsigned int mb =
          (idx < 4 ? (mk0 >> (8 * idx)) : (mk1 >> (8 * (idx - 4)))) & 0xFFu;
      au[idx] = mb ? f2bf(p) : (unsigned short)0;
    }
    bf16x8_t af = __builtin_bit_cast(bf16x8_t, au);
#pragma unroll
    for (int nt = 0; nt < 4; ++nt) {
      ushort8_t bu =
          *(const ushort8_t*)(whb + (size_t)(nt * 16 + m) * NC + jq);
      bf16x8_t bf = __builtin_bit_cast(bf16x8_t, bu);
      acc[nt] = __builtin_amdgcn_mfma_f32_16x16x32_bf16(af, bf, acc[nt], 0, 0, 0);
    }
  }

  // cross-wave reduce + epilogue
#pragma unroll
  for (int nt = 0; nt < 4; ++nt) {
#pragma unroll
    for (int i2 = 0; i2 < 4; ++i2) {
      red_sh[wave * (16 * RSTRIDE) + (q * 4 + i2) * RSTRIDE + nt * 16 + m] =
          acc[nt][i2];
    }
  }
  __syncthreads();

  {
    const int row = t >> 4;
    const int f0 = (t & 15) * 4;
    const float* rp = red_sh + row * RSTRIDE + f0;
    float4 v0 = *(const float4*)(rp + 0 * (16 * RSTRIDE));
    float4 v1 = *(const float4*)(rp + 1 * (16 * RSTRIDE));
    float4 v2 = *(const float4*)(rp + 2 * (16 * RSTRIDE));
    float4 v3 = *(const float4*)(rp + 3 * (16 * RSTRIDE));
    const float inv = rinv_sh[row];
    float4 o;
    o.x = fmaxf((v0.x + v1.x + v2.x + v3.x) * inv, 0.f);
    o.y = fmaxf((v0.y + v1.y + v2.y + v3.y) * inv, 0.f);
    o.z = fmaxf((v0.z + v1.z + v2.z + v3.z) * inv, 0.f);
    o.w = fmaxf((v0.w + v1.w + v2.w + v3.w) * inv, 0.f);
    *(float4*)(out + (size_t)(b * NC + i0 + row) * NF + f0) = o;
  }
}

extern "C" void kernel_launch(void* const* d_in, const int* in_sizes, int n_in,
                              void* d_out, int out_size, void* d_ws, size_t ws_size,
                              hipStream_t stream) {
  const float* H = (const float*)d_in[0];
  const int* A = (const int*)d_in[1];
  const float* W = (const float*)d_in[2];
  const float* avec = (const float*)d_in[3];
  float* out = (float*)d_out;

  char* ws = (char*)d_ws;
  unsigned short* WhT = (unsigned short*)ws;                    // 2 MB
  float* s1 = (float*)(ws + (size_t)NB * NF * NC * 2);          // 64 KB
  float* s2 = s1 + NB * NC;                                     // 64 KB

  k1_prep<<<dim3(NB * (NC / 64)), dim3(256), 0, stream>>>(H, W, avec, s1, s2, WhT);
  k2_attn<<<dim3(NB * (NC / 16)), dim3(256), 0, stream>>>(A, s1, s2, WhT, out);
}

// Round 2
// 227.014 us; speedup vs baseline: 1.0901x; 1.0901x over previous
//
#include <hip/hip_runtime.h>

#define NB 8
#define NC 2048
#define KIN 128
#define NF 64

#define WTSTRIDE 136          // k1 LDS W^T row stride (ushorts)
#define RSTRIDE 68            // k2 reduce row stride (floats)
#define MOFF 60.0f            // softmax shift slack: p <= e^60, underflow at e-m < -147

typedef float floatx4_t __attribute__((ext_vector_type(4)));
typedef __bf16 bf16x8_t __attribute__((ext_vector_type(8)));
typedef unsigned short ushort8_t __attribute__((ext_vector_type(8)));

static __device__ __forceinline__ unsigned short f2bf(float f) {
  union { float f; unsigned int u; } v; v.f = f;
  unsigned int u = v.u;
  u += 0x7FFFu + ((u >> 16) & 1u);   // RNE; inputs never NaN
  return (unsigned short)(u >> 16);
}

static __device__ __forceinline__ float lrelu(float x) {
  return fmaxf(x, 0.2f * x);
}

// ---------------------------------------------------------------------------
// Kernel 1: per block = 64 rows of one batch.
//   - w1 = W@a1, w2 = W@a2; s1/s2 fp32-exact via H@(W@a) (4 threads per row)
//   - WhT[b,f,c] = bf16((H@W)^T) via MFMA: D = W^T (f x k) · H^T (k x c),
//     H^T fragments loaded straight from global (no Hsh, single barrier).
// ---------------------------------------------------------------------------
__global__ __launch_bounds__(256, 2) void k1_prep(
    const float* __restrict__ H, const float* __restrict__ W,
    const float* __restrict__ avec,
    float* __restrict__ s1g, float* __restrict__ s2g,
    unsigned short* __restrict__ WhT)
{
  __shared__ unsigned short WTsh[NF * WTSTRIDE];   // 17.4 KB
  __shared__ float w1sh[KIN];
  __shared__ float w2sh[KIN];

  const int t = threadIdx.x;
  const int b = blockIdx.x >> 5;
  const int c0 = (blockIdx.x & 31) * 64;

  // build bf16 W^T in LDS (coalesced global read)
  for (int i = t; i < KIN * NF; i += 256) {
    int k = i >> 6, f = i & 63;
    WTsh[f * WTSTRIDE + k] = f2bf(W[i]);
  }
  // w1/w2 (fp32 exact)
  if (t < KIN) {
    float acc1 = 0.f, acc2 = 0.f;
    const float* wr = W + t * NF;
#pragma unroll
    for (int f = 0; f < NF; ++f) {
      float wv = wr[f];
      acc1 += wv * avec[f];
      acc2 += wv * avec[NF + f];
    }
    w1sh[t] = acc1;
    w2sh[t] = acc2;
  }
  __syncthreads();

  // ---- phase 1: s1/s2, 4 threads per row, 32 cols each ----
  {
    const int r = t >> 2;          // 0..63
    const int qq = t & 3;
    const float* hp = H + (size_t)(b * NC + c0 + r) * KIN + qq * 32;
    const float* w1p = w1sh + qq * 32;
    const float* w2p = w2sh + qq * 32;
    float p1 = 0.f, p2 = 0.f;
#pragma unroll
    for (int j = 0; j < 8; ++j) {
      float4 h = *(const float4*)(hp + j * 4);
      float4 u1 = *(const float4*)(w1p + j * 4);
      float4 u2 = *(const float4*)(w2p + j * 4);
      p1 += h.x * u1.x + h.y * u1.y + h.z * u1.z + h.w * u1.w;
      p2 += h.x * u2.x + h.y * u2.y + h.z * u2.z + h.w * u2.w;
    }
    p1 += __shfl_xor(p1, 1); p2 += __shfl_xor(p2, 1);
    p1 += __shfl_xor(p1, 2); p2 += __shfl_xor(p2, 2);
    if (qq == 0) {
      s1g[b * NC + c0 + r] = p1;
      s2g[b * NC + c0 + r] = p2;
    }
  }

  // ---- phase 2: MFMA, D = W^T · H^T (M = f = 64, N = c = 16/wave, K = 128)
  const int wave = t >> 6;
  const int lane = t & 63;
  const int m = lane & 15;   // A-row (f sub) and B-col (c sub)
  const int q = lane >> 4;
  floatx4_t acc[4];
#pragma unroll
  for (int mt = 0; mt < 4; ++mt) acc[mt] = (floatx4_t){0.f, 0.f, 0.f, 0.f};

  const float* hb = H + (size_t)(b * NC + c0 + wave * 16 + m) * KIN;
#pragma unroll
  for (int kt = 0; kt < 4; ++kt) {
    const int kbase = kt * 32 + q * 8;
    float4 h0 = *(const float4*)(hb + kbase);
    float4 h1 = *(const float4*)(hb + kbase + 4);
    ushort8_t bu;
    bu[0] = f2bf(h0.x); bu[1] = f2bf(h0.y); bu[2] = f2bf(h0.z); bu[3] = f2bf(h0.w);
    bu[4] = f2bf(h1.x); bu[5] = f2bf(h1.y); bu[6] = f2bf(h1.z); bu[7] = f2bf(h1.w);
    bf16x8_t bf = __builtin_bit_cast(bf16x8_t, bu);
#pragma unroll
    for (int mt = 0; mt < 4; ++mt) {
      ushort8_t au = *(const ushort8_t*)(WTsh + (mt * 16 + m) * WTSTRIDE + kbase);
      bf16x8_t af = __builtin_bit_cast(bf16x8_t, au);
      acc[mt] = __builtin_amdgcn_mfma_f32_16x16x32_bf16(af, bf, acc[mt], 0, 0, 0);
    }
  }
  // D[row = q*4+i2 -> f][col = m -> c]
#pragma unroll
  for (int mt = 0; mt < 4; ++mt) {
#pragma unroll
    for (int i2 = 0; i2 < 4; ++i2) {
      const int f = mt * 16 + q * 4 + i2;
      WhT[(size_t)(b * NF + f) * NC + c0 + wave * 16 + m] = f2bf(acc[mt][i2]);
    }
  }
}

// ---------------------------------------------------------------------------
// Kernel 2: per block = 16 query rows of one batch. Single pass over A:
// mask -> exp -> bf16 -> MFMA (4 Wh tiles + 1 ones-tile giving row sums).
// ---------------------------------------------------------------------------
__global__ __launch_bounds__(256, 2) void k2_attn(
    const int* __restrict__ A, const float* __restrict__ s1g,
    const float* __restrict__ s2g, const unsigned short* __restrict__ WhT,
    float* __restrict__ out)
{
  __shared__ float s2_sh[NC];                   // 8 KB
  __shared__ float s1_sh[16];
  __shared__ float wmax_sh[4];
  __shared__ float red_sh[4 * 16 * RSTRIDE];    // 17.4 KB
  __shared__ float lsum_sh[4 * 16];

  const int t = threadIdx.x;
  const int b = blockIdx.x >> 7;
  const int i0 = (blockIdx.x & 127) * 16;
  const int wave = t >> 6;
  const int lane = t & 63;

  // stage s2 (two coalesced float4 sweeps) + batch-max of s2
  float lmax;
  {
    const float* sp = s2g + b * NC;
    float4 v0 = *(const float4*)(sp + t * 4);
    float4 v1 = *(const float4*)(sp + 1024 + t * 4);
    *(float4*)(s2_sh + t * 4) = v0;
    *(float4*)(s2_sh + 1024 + t * 4) = v1;
    lmax = fmaxf(fmaxf(fmaxf(v0.x, v0.y), fmaxf(v0.z, v0.w)),
                 fmaxf(fmaxf(v1.x, v1.y), fmaxf(v1.z, v1.w)));
#pragma unroll
    for (int off = 1; off < 64; off <<= 1)
      lmax = fmaxf(lmax, __shfl_xor(lmax, off));
    if (lane == 0) wmax_sh[wave] = lmax;
  }
  if (t < 16) s1_sh[t] = s1g[b * NC + i0 + t];
  __syncthreads();

  const float s2max =
      fmaxf(fmaxf(wmax_sh[0], wmax_sh[1]), fmaxf(wmax_sh[2], wmax_sh[3]));

  const int m = lane & 15;   // A-frag row (query sub) and B-frag col (f sub)
  const int q = lane >> 4;
  const int gi = i0 + m;
  const float s1m = s1_sh[m];
  const float mm = lrelu(s1m + s2max) - MOFF;   // upper bound minus slack
  const int* Ap = A + ((size_t)b * NC + gi) * NC;
  const unsigned short* whb = WhT + (size_t)b * NF * NC;

  // ones B-fragment: column 0 of tile = 1.0 -> accl col0 = row sums of P
  ushort8_t ou;
  {
    const unsigned short ov = (m == 0) ? (unsigned short)0x3F80 : (unsigned short)0;
#pragma unroll
    for (int idx = 0; idx < 8; ++idx) ou[idx] = ov;
  }
  const bf16x8_t onesf = __builtin_bit_cast(bf16x8_t, ou);

  floatx4_t acc[4], accl;
#pragma unroll
  for (int nt = 0; nt < 4; ++nt) acc[nt] = (floatx4_t){0.f, 0.f, 0.f, 0.f};
  accl = (floatx4_t){0.f, 0.f, 0.f, 0.f};

  const int ktBeg = wave * 16, ktEnd = wave * 16 + 16;
  int4 pa0, pa1;
  {
    const int* ap = Ap + ktBeg * 32 + q * 8;
    pa0 = *(const int4*)ap;
    pa1 = *(const int4*)(ap + 4);
  }

  for (int kt = ktBeg; kt < ktEnd; ++kt) {
    const int4 a0 = pa0, a1 = pa1;
    if (kt + 1 < ktEnd) {
      const int* ap = Ap + (kt + 1) * 32 + q * 8;
      pa0 = *(const int4*)ap;
      pa1 = *(const int4*)(ap + 4);
    }
    const int jq = kt * 32 + q * 8;
    float4 s0 = *(const float4*)(s2_sh + jq);
    float4 s1v = *(const float4*)(s2_sh + jq + 4);
    const float sv[8] = {s0.x, s0.y, s0.z, s0.w, s1v.x, s1v.y, s1v.z, s1v.w};
    const int av[8] = {a0.x, a0.y, a0.z, a0.w, a1.x, a1.y, a1.z, a1.w};
    ushort8_t au;
#pragma unroll
    for (int idx = 0; idx < 8; ++idx) {
      float x = s1m + sv[idx];
      float p = __expf(lrelu(x) - mm);
      bool keep = (av[idx] > 0) || (jq + idx == gi);
      au[idx] = keep ? f2bf(p) : (unsigned short)0;
    }
    const bf16x8_t af = __builtin_bit_cast(bf16x8_t, au);
#pragma unroll
    for (int nt = 0; nt < 4; ++nt) {
      ushort8_t bu = *(const ushort8_t*)(whb + (size_t)(nt * 16 + m) * NC + jq);
      bf16x8_t bf = __builtin_bit_cast(bf16x8_t, bu);
      acc[nt] = __builtin_amdgcn_mfma_f32_16x16x32_bf16(af, bf, acc[nt], 0, 0, 0);
    }
    accl = __builtin_amdgcn_mfma_f32_16x16x32_bf16(af, onesf, accl, 0, 0, 0);
  }

  // cross-wave reduce: acc D[row=q*4+i2][col=m(+nt*16)], lsum from accl col 0
#pragma unroll
  for (int nt = 0; nt < 4; ++nt) {
#pragma unroll
    for (int i2 = 0; i2 < 4; ++i2) {
      red_sh[wave * (16 * RSTRIDE) + (q * 4 + i2) * RSTRIDE + nt * 16 + m] =
          acc[nt][i2];
    }
  }
  if (m == 0) {
#pragma unroll
    for (int i2 = 0; i2 < 4; ++i2)
      lsum_sh[wave * 16 + q * 4 + i2] = accl[i2];
  }
  __syncthreads();

  {
    const int row = t >> 4;
    const int f0 = (t & 15) * 4;
    float4 v = {0.f, 0.f, 0.f, 0.f};
    float ls = 0.f;
#pragma unroll
    for (int w = 0; w < 4; ++w) {
      const float* rp = red_sh + w * (16 * RSTRIDE) + row * RSTRIDE + f0;
      float4 vv = *(const float4*)rp;
      v.x += vv.x; v.y += vv.y; v.z += vv.z; v.w += vv.w;
      ls += lsum_sh[w * 16 + row];
    }
    const float inv = 1.0f / ls;
    float4 o;
    o.x = fmaxf(v.x * inv, 0.f);
    o.y = fmaxf(v.y * inv, 0.f);
    o.z = fmaxf(v.z * inv, 0.f);
    o.w = fmaxf(v.w * inv, 0.f);
    *(float4*)(out + (size_t)(b * NC + i0 + row) * NF + f0) = o;
  }
}

extern "C" void kernel_launch(void* const* d_in, const int* in_sizes, int n_in,
                              void* d_out, int out_size, void* d_ws, size_t ws_size,
                              hipStream_t stream) {
  const float* H = (const float*)d_in[0];
  const int* A = (const int*)d_in[1];
  const float* W = (const float*)d_in[2];
  const float* avec = (const float*)d_in[3];
  float* out = (float*)d_out;

  char* ws = (char*)d_ws;
  unsigned short* WhT = (unsigned short*)ws;                    // 2 MB
  float* s1 = (float*)(ws + (size_t)NB * NF * NC * 2);          // 64 KB
  float* s2 = s1 + NB * NC;                                     // 64 KB

  k1_prep<<<dim3(NB * (NC / 64)), dim3(256), 0, stream>>>(H, W, avec, s1, s2, WhT);
  k2_attn<<<dim3(NB * (NC / 16)), dim3(256), 0, stream>>>(A, s1, s2, WhT, out);
}